// Round 4
// baseline (3304.048 us; speedup 1.0000x reference)
//
#include <hip/hip_runtime.h>
#include <math.h>

#define AGENTS __HIP_MEMORY_SCOPE_AGENT
typedef unsigned long long u64x;

constexpr int   CB   = 16;      // batches
constexpr int   CN   = 16384;   // rows per batch
constexpr float LOG7 = 1.9459101090932196f;
constexpr float EPST = 1e-8f;

// ---- u64 stamp regions (u64 indices from ws start) ----
constexpr size_t ST1 = 0;       // [16][16][2]    phase-0 stats (mx,se), epoch==1
constexpr size_t ST2 = 512;     // [16][2][4][8]  sweep partials, epoch-stamped
constexpr size_t ST3 = 1536;    // [16][2][4][448] update partials
constexpr size_t NST = 58880;

// ---- float offsets ----
constexpr size_t OFF_LG  = 117760;                  // [16][16384] logits
constexpr size_t OFF_WQT = 379904;                  // [64][64]
constexpr size_t OFF_WIH = 384000;                  // [64][192]
constexpr size_t OFF_WHH = 396288;                  // [64][192]
constexpr size_t OFF_F1T = 408576;                  // [64][128]
constexpr size_t OFF_F2T = 416768;                  // [128][64]
constexpr size_t OFF_K   = 424960;                  // [16][16384][64]
constexpr size_t OFF_V   = OFF_K + (size_t)CB * CN * 64;

__device__ __forceinline__ u64x pk(float v, unsigned e) {
  return ((u64x)e << 32) | (u64x)__float_as_uint(v);
}
__device__ __forceinline__ void st_rlx(u64x* p, u64x v) {
  __hip_atomic_store(p, v, __ATOMIC_RELAXED, AGENTS);
}
__device__ __forceinline__ float poll_val(const u64x* p, unsigned e) {
  u64x q;
  do {
    q = __hip_atomic_load(const_cast<u64x*>(p), __ATOMIC_RELAXED, AGENTS);
  } while ((unsigned)(q >> 32) != e);
  return __uint_as_float((unsigned)q);
}
__device__ __forceinline__ float wsum64(float v) {
#pragma unroll
  for (int m = 1; m < 64; m <<= 1) v += __shfl_xor(v, m, 64);
  return v;
}
__device__ __forceinline__ float dot4(float4 a, float4 b) {
  return a.x * b.x + a.y * b.y + a.z * b.z + a.w * b.w;
}

__global__ void prep_kernel(const float* __restrict__ Wq, const float* __restrict__ Wih,
                            const float* __restrict__ Whh, const float* __restrict__ f1,
                            const float* __restrict__ f2, float* __restrict__ w) {
  int idx = blockIdx.x * blockDim.x + threadIdx.x;
  int stride = gridDim.x * blockDim.x;
  u64x* st = reinterpret_cast<u64x*>(w);
  for (size_t i = idx; i < NST; i += stride) st_rlx(st + i, 0ULL);
  for (int i = idx; i < 64 * 64; i += stride) {
    int d = i / 64, j = i % 64;
    w[OFF_WQT + j * 64 + d] = Wq[d * 64 + j];
  }
  for (int i = idx; i < 192 * 64; i += stride) {
    int o = i / 64, j = i % 64;
    w[OFF_WIH + j * 192 + o] = Wih[o * 64 + j];
    w[OFF_WHH + j * 192 + o] = Whh[o * 64 + j];
  }
  for (int i = idx; i < 128 * 64; i += stride) {
    int o = i / 64, j = i % 64;
    w[OFF_F1T + j * 128 + o] = f1[o * 64 + j];
  }
  for (int i = idx; i < 64 * 128; i += stride) {
    int d = i / 128, j = i % 128;
    w[OFF_F2T + j * 64 + d] = f2[d * 128 + j];
  }
}

__launch_bounds__(1024, 4)
__global__ void slot_attn_kernel(
    const float* __restrict__ inputs, const float* __restrict__ sinit,
    const float* __restrict__ smu, const float* __restrict__ slsig,
    const float* __restrict__ Wk, const float* __restrict__ Wv,
    const float* __restrict__ gbih, const float* __restrict__ gbhh,
    const float* __restrict__ fc1b, const float* __restrict__ fc2b,
    const float* __restrict__ lin_g, const float* __restrict__ lin_b,
    const float* __restrict__ lsl_g, const float* __restrict__ lsl_b,
    const float* __restrict__ lff_g, const float* __restrict__ lff_b,
    const float* __restrict__ wi_W, const float* __restrict__ wi_b,
    const float* __restrict__ wsW, const float* __restrict__ wsB,
    float* __restrict__ out, float* __restrict__ w) {
  __shared__ float s_slots[448];
  __shared__ float s_snl[448];
  __shared__ float s_q[448];
  __shared__ float s_scr1[1344];
  __shared__ float s_scr2[1344];
  __shared__ float s_updl[448];
  __shared__ float s_T[8192];       // [1024][8]
  __shared__ float s_pupd[7168];    // [16][7][64]
  __shared__ float s_vh[48];        // v history [6][8]
  __shared__ float s_logb[8];
  __shared__ float s_gvl[8];
  __shared__ float s_q2[8];
  __shared__ float s_wl[8];
  __shared__ float s_redw[128];     // [16][8]
  __shared__ float s_part[32];
  __shared__ float s_misc[4];

  const int tid = threadIdx.x;
  const int lane = tid & 63, wid = tid >> 6;
  const int bb = blockIdx.x & 15;
  const int ib = blockIdx.x >> 4;
  u64x* st = reinterpret_cast<u64x*>(w);
  float lg;

  // ================= phase 0 (all 256 blocks): LN + k/v/logit =================
  {
    const size_t grow = (size_t)bb * CN + ib * 1024 + tid;
    const float* xin = inputs + grow * 64;
    float4 xa[16];
#pragma unroll
    for (int c = 0; c < 16; ++c) xa[c] = reinterpret_cast<const float4*>(xin)[c];
    float s1 = 0;
#pragma unroll
    for (int c = 0; c < 16; ++c) s1 += xa[c].x + xa[c].y + xa[c].z + xa[c].w;
    float mn = s1 * (1.f / 64.f);
    float s2 = 0;
#pragma unroll
    for (int c = 0; c < 16; ++c) {
      float dx = xa[c].x - mn, dy = xa[c].y - mn, dz = xa[c].z - mn, dw = xa[c].w - mn;
      s2 += dx * dx + dy * dy + dz * dz + dw * dw;
    }
    float rs = rsqrtf(s2 * (1.f / 64.f) + 1e-5f);
#pragma unroll
    for (int c = 0; c < 16; ++c) {
      float4 g4 = reinterpret_cast<const float4*>(lin_g)[c];
      float4 b4 = reinterpret_cast<const float4*>(lin_b)[c];
      xa[c].x = (xa[c].x - mn) * rs * g4.x + b4.x;
      xa[c].y = (xa[c].y - mn) * rs * g4.y + b4.y;
      xa[c].z = (xa[c].z - mn) * rs * g4.z + b4.z;
      xa[c].w = (xa[c].w - mn) * rs * g4.w + b4.w;
    }
    lg = wi_b[0];
#pragma unroll
    for (int c = 0; c < 16; ++c) lg += dot4(xa[c], reinterpret_cast<const float4*>(wi_W)[c]);
    w[OFF_LG + grow] = lg;
#pragma unroll 1
    for (int half = 0; half < 2; ++half) {
      const float* W = half ? Wv : Wk;
      float* ob = w + (half ? OFF_V : OFF_K) + grow * 64;
#pragma unroll 1
      for (int oc = 0; oc < 8; ++oc) {
        float acc[8] = {0, 0, 0, 0, 0, 0, 0, 0};
#pragma unroll
        for (int c = 0; c < 16; ++c) {
          float4 xv = xa[c];
#pragma unroll
          for (int o8 = 0; o8 < 8; ++o8) {
            float4 w4 = reinterpret_cast<const float4*>(W + (size_t)(oc * 8 + o8) * 64)[c];
            acc[o8] += dot4(xv, w4);
          }
        }
        reinterpret_cast<float4*>(ob + oc * 8)[0] = make_float4(acc[0], acc[1], acc[2], acc[3]);
        reinterpret_cast<float4*>(ob + oc * 8)[1] = make_float4(acc[4], acc[5], acc[6], acc[7]);
      }
    }
    // local softmax stats over this block's 1024 rows
    float mx = lg;
#pragma unroll
    for (int m = 1; m < 64; m <<= 1) mx = fmaxf(mx, __shfl_xor(mx, m, 64));
    float se = wsum64(__expf(lg - mx));
    if (lane == 0) { s_redw[wid * 8 + 0] = mx; s_redw[wid * 8 + 1] = se; }
    asm volatile("s_waitcnt vmcnt(0)" ::: "memory");  // k/v/lg stores acked to L2
    __syncthreads();
    if (wid == 0) {
      float m0 = (lane < 16) ? s_redw[lane * 8 + 0] : -1e30f;
      float e0 = (lane < 16) ? s_redw[lane * 8 + 1] : 0.f;
#pragma unroll
      for (int mm = 1; mm < 16; mm <<= 1) {
        float m1 = __shfl_xor(m0, mm, 64), e1 = __shfl_xor(e0, mm, 64);
        float nm = fmaxf(m0, m1);
        e0 = e0 * __expf(m0 - nm) + e1 * __expf(m1 - nm);
        m0 = nm;
      }
      __threadfence();   // wbl2: flush this XCD's L2 (k/v/lg) before publishing
      if (lane == 0) {
        st_rlx(st + ST1 + ((size_t)bb * 16 + ib) * 2 + 0, pk(m0, 1u));
        st_rlx(st + ST1 + ((size_t)bb * 16 + ib) * 2 + 1, pk(e0, 1u));
      }
    }
  }

  if (ib & 3) return;               // 64 survivors: 4 per batch
  const int sc = ib >> 2;           // sub-chunk 0..3; rows sc*4096 + r*1024 + tid

  // ---- gather stats (16 blocks), compute lse; acquire-fence then load lg ----
  if (wid == 0) {
    float m0 = -1e30f, e0 = 0.f;
    if (lane < 16) {
      m0 = poll_val(st + ST1 + ((size_t)bb * 16 + lane) * 2 + 0, 1u);
      e0 = poll_val(st + ST1 + ((size_t)bb * 16 + lane) * 2 + 1, 1u);
    }
#pragma unroll
    for (int mm = 1; mm < 16; mm <<= 1) {
      float m1 = __shfl_xor(m0, mm, 64), e1 = __shfl_xor(e0, mm, 64);
      float nm = fmaxf(m0, m1);
      e0 = e0 * __expf(m0 - nm) + e1 * __expf(m1 - nm);
      m0 = nm;
    }
    __threadfence();   // inv: later plain reads of k/v/lg see fresh data
    if (lane == 0) s_misc[0] = m0 + __logf(e0);
  }
  __syncthreads();
  float log_a[4];
  {
    float lse = s_misc[0];
    log_a[0] = lg - lse + LOG7;     // own phase-0 rows are r=0 of this chunk
#pragma unroll
    for (int r = 1; r < 4; ++r) {
      float lgr = w[OFF_LG + (size_t)bb * CN + sc * 4096 + r * 1024 + tid];
      log_a[r] = lgr - lse + LOG7;
    }
  }

  unsigned e = 2;                   // epoch counter (stats used 1)
  float p[4][7], u[4];

  // ---- stamped 4-block all-reduce of 7 per-thread values ----
  auto exchange4 = [&](float (&es)[7], float* dst8, bool to_vh) {
#pragma unroll
    for (int m = 1; m < 64; m <<= 1) {
#pragma unroll
      for (int s = 0; s < 7; ++s) es[s] += __shfl_xor(es[s], m, 64);
    }
    if (lane < 7) s_redw[wid * 8 + lane] = es[lane];
    __syncthreads();
    const unsigned par = e & 1;
    u64x* sl2 = st + ST2 + ((size_t)(bb * 2 + par) * 4) * 8;
    if (wid == 0) {
      float bp[2]; int ss[2];
#pragma unroll
      for (int h = 0; h < 2; ++h) {
        int s = h * 4 + (lane >> 4); ss[h] = s;
        float v = (s < 7) ? s_redw[(lane & 15) * 8 + s] : 0.f;
        v += __shfl_xor(v, 1, 64); v += __shfl_xor(v, 2, 64);
        v += __shfl_xor(v, 4, 64); v += __shfl_xor(v, 8, 64);
        bp[h] = v;
      }
      if ((lane & 15) == 0) {
#pragma unroll
        for (int h = 0; h < 2; ++h) {
          if (ss[h] < 7) {
            st_rlx(sl2 + sc * 8 + ss[h], pk(bp[h], e));
            s_part[24 + ss[h]] = bp[h];
          }
        }
      }
      int rj = lane >> 3, s = lane & 7;
      if (rj < 3 && s < 7) {
        int rsc = rj + (rj >= sc);
        s_part[rj * 8 + s] = poll_val(sl2 + rsc * 8 + s, e);
      }
      if (lane < 7) {
        float tot = s_part[lane] + s_part[8 + lane] + s_part[16 + lane] + s_part[24 + lane];
        dst8[lane] = to_vh ? (s_logb[lane] - __logf(tot)) : tot;
      }
    }
    __syncthreads();
    ++e;
  };

  auto fwd5 = [&]() {
#pragma unroll 1
    for (int i = 1; i <= 5; ++i) {
      float es[7] = {0, 0, 0, 0, 0, 0, 0};
#pragma unroll
      for (int r = 0; r < 4; ++r) {
        float t = 0;
#pragma unroll
        for (int s = 0; s < 7; ++s) t += __expf(p[r][s] + s_vh[(i - 1) * 8 + s]);
        u[r] = log_a[r] - __logf(t);
#pragma unroll
        for (int s = 0; s < 7; ++s) es[s] += __expf(p[r][s] + u[r]);
      }
      exchange4(es, s_vh + i * 8, true);
    }
  };

  // slot phase common: LN(slots)->snl, q into LDS, log_b
  auto slot_common = [&]() {
    if (wid < 7) {
      float h = s_slots[wid * 64 + lane];
      float m = wsum64(h) * (1.f / 64.f);
      float d0 = h - m;
      float va = wsum64(d0 * d0) * (1.f / 64.f);
      float sn = d0 * rsqrtf(va + 1e-5f) * lsl_g[lane] + lsl_b[lane];
      s_snl[wid * 64 + lane] = sn;
      float pw = wsum64(sn * wsW[lane]);
      if (lane == 0) s_wl[wid] = pw + wsB[0];
    }
    __syncthreads();
    if (tid < 448) {
      int s = tid >> 6, dd = tid & 63;
      float acc = 0;
#pragma unroll 4
      for (int j = 0; j < 64; ++j) acc += s_snl[s * 64 + j] * w[OFF_WQT + j * 64 + dd];
      s_q[s * 64 + dd] = acc;
    }
    __syncthreads();
    if (wid < 7) {
      float qv = s_q[wid * 64 + lane];
      float q2 = wsum64(qv * qv);
      if (lane == 0) s_q2[wid] = q2;
    }
    if (tid == 0) {
      float mx = -1e30f;
#pragma unroll
      for (int s = 0; s < 7; ++s) mx = fmaxf(mx, s_wl[s]);
      float se = 0;
#pragma unroll
      for (int s = 0; s < 7; ++s) se += __expf(s_wl[s] - mx);
      float lse = mx + __logf(se);
#pragma unroll
      for (int s = 0; s < 7; ++s) s_logb[s] = s_wl[s] - lse + LOG7;
    }
    __syncthreads();
  };

  // init slots
  if (tid < 448) {
    int dd = tid & 63;
    s_slots[tid] = smu[dd] + __expf(slsig[dd]) * sinit[(size_t)bb * 448 + tid];
  }
  __syncthreads();
  slot_common();

#pragma unroll 1
  for (int it = 0; it < 3; ++it) {
    // ---- C = -cdist(k, q), 4 rows/thread ----
#pragma unroll 1
    for (int r = 0; r < 4; ++r) {
      const float* kb = w + OFF_K + ((size_t)bb * CN + sc * 4096 + r * 1024 + tid) * 64;
      float4 ka[16];
#pragma unroll
      for (int c = 0; c < 16; ++c) ka[c] = reinterpret_cast<const float4*>(kb)[c];
      float k2 = 0;
#pragma unroll
      for (int c = 0; c < 16; ++c) k2 += dot4(ka[c], ka[c]);
#pragma unroll
      for (int s = 0; s < 7; ++s) {
        float kq = 0;
#pragma unroll
        for (int c = 0; c < 16; ++c)
          kq += dot4(ka[c], *reinterpret_cast<const float4*>(&s_q[s * 64 + c * 4]));
        float sq = k2 + s_q2[s] - 2.f * kq;
        p[r][s] = -sqrtf(fmaxf(sq, 0.f) + 1e-12f);
      }
    }
    if (tid < 8) s_vh[tid] = 0.f;
    __syncthreads();

    // ---- MESH: 4 iterations ----
#pragma unroll 1
    for (int ms = 0; ms < 4; ++ms) {
      fwd5();
      float gp[4][7], gu0[4];
      {
        float es[7] = {0, 0, 0, 0, 0, 0, 0};
#pragma unroll
        for (int r = 0; r < 4; ++r) {
          gu0[r] = 0.f;
#pragma unroll
          for (int s = 0; s < 7; ++s) {
            float T = __expf(p[r][s] + u[r] + s_vh[40 + s]);
            float gT = -(__logf(T + EPST) + T / (T + EPST));
            float g = gT * T;
            gp[r][s] = g; gu0[r] += g; es[s] += g;
          }
        }
        exchange4(es, s_gvl, false);
      }
#pragma unroll 1
      for (int i = 5; i >= 1; --i) {
        float es[7] = {0, 0, 0, 0, 0, 0, 0};
#pragma unroll
        for (int r = 0; r < 4; ++r) {
          float t = 0;
#pragma unroll
          for (int s = 0; s < 7; ++s) t += __expf(p[r][s] + s_vh[(i - 1) * 8 + s]);
          float ui = log_a[r] - __logf(t);
          float gu = (i == 5) ? gu0[r] : 0.f;
#pragma unroll
          for (int s = 0; s < 7; ++s) {
            float sn = __expf(p[r][s] + ui - s_logb[s] + s_vh[i * 8 + s]);
            float gz = -s_gvl[s] * sn;
            gp[r][s] += gz; gu += gz;
          }
#pragma unroll
          for (int s = 0; s < 7; ++s) {
            float sg = __expf(p[r][s] + s_vh[(i - 1) * 8 + s] - log_a[r] + ui);
            float gw = -gu * sg;
            gp[r][s] += gw; es[s] += gw;
          }
        }
        if (i > 1) exchange4(es, s_gvl, false);
      }
#pragma unroll
      for (int r = 0; r < 4; ++r)
#pragma unroll
        for (int s = 0; s < 7; ++s) p[r][s] -= 5.0f * gp[r][s];
      if (tid < 8) s_vh[tid] = s_vh[40 + tid];
      __syncthreads();
    }

    // ---- final sinkhorn -> T, attn out, updates ----
    fwd5();
    float acc[7] = {0, 0, 0, 0, 0, 0, 0};
#pragma unroll 1
    for (int r = 0; r < 4; ++r) {
      float tv[7];
#pragma unroll
      for (int s = 0; s < 7; ++s) tv[s] = __expf(p[r][s] + u[r] + s_vh[40 + s]);
      if (it == 2) {
        size_t rowg = (size_t)sc * 4096 + r * 1024 + tid;
#pragma unroll
        for (int s = 0; s < 7; ++s)
          out[7168 + ((size_t)(bb * 7 + s)) * CN + rowg] = tv[s];
      }
#pragma unroll
      for (int s = 0; s < 7; ++s) s_T[tid * 8 + s] = tv[s];
      __syncthreads();
      const float* vb = w + OFF_V +
          ((size_t)bb * CN + sc * 4096 + r * 1024 + wid * 64) * 64 + lane;
#pragma unroll 4
      for (int n = 0; n < 64; ++n) {
        float vv = vb[(size_t)n * 64];
        const float* tr = &s_T[(wid * 64 + n) * 8];
        acc[0] += tr[0] * vv; acc[1] += tr[1] * vv; acc[2] += tr[2] * vv;
        acc[3] += tr[3] * vv; acc[4] += tr[4] * vv; acc[5] += tr[5] * vv;
        acc[6] += tr[6] * vv;
      }
      __syncthreads();
    }
#pragma unroll
    for (int s = 0; s < 7; ++s) s_pupd[(wid * 7 + s) * 64 + lane] = acc[s];
    __syncthreads();
    {
      const unsigned par = e & 1;
      u64x* sl3 = st + ST3 + ((size_t)(bb * 2 + par) * 4) * 448;
      if (tid < 448) {
        float t = 0;
#pragma unroll
        for (int w16 = 0; w16 < 16; ++w16) t += s_pupd[w16 * 448 + tid];
        st_rlx(sl3 + sc * 448 + tid, pk(t, e));
        float tot = 0;
#pragma unroll 1
        for (int j = 0; j < 4; ++j)
          tot += (j == sc) ? t : poll_val(sl3 + (size_t)j * 448 + tid, e);
        s_updl[tid] = tot;
      }
      __syncthreads();
      ++e;
    }

    // ---- GRU cell + FF (redundant per survivor) ----
    {
#pragma unroll 1
      for (int idx = tid; idx < 1344; idx += 1024) {
        int s = idx / 192, o = idx - s * 192;
        float g1 = gbih[o], g2 = gbhh[o];
#pragma unroll 4
        for (int j = 0; j < 64; ++j) {
          g1 += s_updl[s * 64 + j] * w[OFF_WIH + j * 192 + o];
          g2 += s_slots[s * 64 + j] * w[OFF_WHH + j * 192 + o];
        }
        s_scr1[s * 192 + o] = g1;
        s_scr2[s * 192 + o] = g2;
      }
      __syncthreads();
      if (tid < 448) {
        int s = tid >> 6, dd = tid & 63;
        float ir = s_scr1[s * 192 + dd],        hr = s_scr2[s * 192 + dd];
        float iz = s_scr1[s * 192 + 64 + dd],   hz = s_scr2[s * 192 + 64 + dd];
        float in_ = s_scr1[s * 192 + 128 + dd], hn = s_scr2[s * 192 + 128 + dd];
        float r = 1.f / (1.f + __expf(-(ir + hr)));
        float z = 1.f / (1.f + __expf(-(iz + hz)));
        float nn = tanhf(in_ + r * hn);
        s_updl[s * 64 + dd] = (1.f - z) * nn + z * s_slots[s * 64 + dd];
      }
      __syncthreads();
      if (wid < 7) {
        float h = s_updl[wid * 64 + lane];
        float m = wsum64(h) * (1.f / 64.f);
        float d0 = h - m;
        float va = wsum64(d0 * d0) * (1.f / 64.f);
        s_snl[wid * 64 + lane] = d0 * rsqrtf(va + 1e-5f) * lff_g[lane] + lff_b[lane];
      }
      __syncthreads();
      if (tid < 896) {
        int s = tid >> 7, i2 = tid & 127;
        float a1 = fc1b[i2];
#pragma unroll 4
        for (int j = 0; j < 64; ++j) a1 += s_snl[s * 64 + j] * w[OFF_F1T + j * 128 + i2];
        s_scr1[s * 128 + i2] = fmaxf(a1, 0.f);
      }
      __syncthreads();
      if (tid < 448) {
        int s = tid >> 6, dd = tid & 63;
        float a2 = fc2b[dd];
#pragma unroll 4
        for (int i2 = 0; i2 < 128; ++i2) a2 += s_scr1[s * 128 + i2] * w[OFF_F2T + i2 * 64 + dd];
        s_slots[s * 64 + dd] = s_updl[s * 64 + dd] + a2;
      }
      __syncthreads();
    }
    if (it < 2) slot_common();
  }

  if (sc == 0 && tid < 448) out[(size_t)bb * 448 + tid] = s_slots[tid];
}

extern "C" void kernel_launch(void* const* d_in, const int* in_sizes, int n_in,
                              void* d_out, int out_size, void* d_ws, size_t ws_size,
                              hipStream_t stream) {
  (void)in_sizes; (void)n_in; (void)out_size; (void)ws_size;
  const float* inputs = (const float*)d_in[0];
  const float* sinit  = (const float*)d_in[1];
  const float* smu    = (const float*)d_in[2];
  const float* slsig  = (const float*)d_in[3];
  const float* Wq     = (const float*)d_in[4];
  const float* Wk     = (const float*)d_in[5];
  const float* Wv     = (const float*)d_in[6];
  const float* gWih   = (const float*)d_in[7];
  const float* gWhh   = (const float*)d_in[8];
  const float* gbih   = (const float*)d_in[9];
  const float* gbhh   = (const float*)d_in[10];
  const float* fc1W   = (const float*)d_in[11];
  const float* fc1b   = (const float*)d_in[12];
  const float* fc2W   = (const float*)d_in[13];
  const float* fc2b   = (const float*)d_in[14];
  const float* ling   = (const float*)d_in[15];
  const float* linb   = (const float*)d_in[16];
  const float* lslg   = (const float*)d_in[17];
  const float* lslb   = (const float*)d_in[18];
  const float* lffg   = (const float*)d_in[19];
  const float* lffb   = (const float*)d_in[20];
  const float* wiW    = (const float*)d_in[21];
  const float* wib    = (const float*)d_in[22];
  const float* wsW    = (const float*)d_in[23];
  const float* wsb    = (const float*)d_in[24];
  float* out = (float*)d_out;
  float* w   = (float*)d_ws;

  prep_kernel<<<dim3(64), dim3(256), 0, stream>>>(Wq, gWih, gWhh, fc1W, fc2W, w);
  slot_attn_kernel<<<dim3(256), dim3(1024), 0, stream>>>(
      inputs, sinit, smu, slsig, Wk, Wv, gbih, gbhh, fc1b, fc2b,
      ling, linb, lslg, lslb, lffg, lffb, wiW, wib, wsW, wsb, out, w);
}

// Round 6
// 1754.572 us; speedup vs baseline: 1.8831x; 1.8831x over previous
//
#include <hip/hip_runtime.h>
#include <math.h>

#define AGENTS __HIP_MEMORY_SCOPE_AGENT
typedef unsigned long long u64x;

constexpr int   CB   = 16;      // batches
constexpr int   CN   = 16384;   // rows per batch
constexpr float LOG7 = 1.9459101090932196f;
constexpr float EPST = 1e-8f;

// ---- u64 stamp regions (u64 indices from ws start) ----
constexpr size_t ST1 = 0;        // [16][16][4]      phase-0 (mx, se), epoch==1
constexpr size_t ST2 = 1024;     // [16][2][16][8]   sweep partials, epoch-stamped
constexpr size_t ST3 = 5120;     // [16][2][16][448] update partials
constexpr size_t NST = 234496;

// ---- float offsets ----
constexpr size_t OFF_WQT = 468992;                  // [64][64]
constexpr size_t OFF_WIH = 473088;                  // [64][192]
constexpr size_t OFF_WHH = 485376;                  // [64][192]
constexpr size_t OFF_F1T = 497664;                  // [64][128]
constexpr size_t OFF_F2T = 505856;                  // [128][64]
constexpr size_t OFF_K   = 514048;                  // [16][16384][64]
constexpr size_t OFF_V   = OFF_K + (size_t)CB * CN * 64;

__device__ __forceinline__ u64x pkf(float v, unsigned e) {
  return ((u64x)e << 32) | (u64x)__float_as_uint(v);
}
__device__ __forceinline__ void st_rlx(u64x* p, u64x v) {
  __hip_atomic_store(p, v, __ATOMIC_RELAXED, AGENTS);
}
__device__ __forceinline__ u64x ld_rlx(const u64x* p) {
  return __hip_atomic_load(const_cast<u64x*>(p), __ATOMIC_RELAXED, AGENTS);
}
// sc1 poll ONLY: agent stores bypass the XCD L2, and an sc0 load would cache a
// stale line forever (no back-invalidation) -> deadlock (round-5 lesson).
__device__ __forceinline__ float poll_f(const u64x* p, unsigned e) {
  u64x q;
  do { q = ld_rlx(p); } while ((unsigned)(q >> 32) != e);
  return __uint_as_float((unsigned)q);
}
__device__ __forceinline__ float wsum64(float v) {
#pragma unroll
  for (int m = 1; m < 64; m <<= 1) v += __shfl_xor(v, m, 64);
  return v;
}
__device__ __forceinline__ float dot4(float4 a, float4 b) {
  return a.x * b.x + a.y * b.y + a.z * b.z + a.w * b.w;
}

__global__ void prep_kernel(const float* __restrict__ Wq, const float* __restrict__ Wih,
                            const float* __restrict__ Whh, const float* __restrict__ f1,
                            const float* __restrict__ f2, float* __restrict__ w) {
  size_t idx = blockIdx.x * blockDim.x + threadIdx.x;
  size_t stride = (size_t)gridDim.x * blockDim.x;
  u64x* st = reinterpret_cast<u64x*>(w);
  for (size_t i = idx; i < NST; i += stride) st_rlx(st + i, 0ULL);
  for (size_t i = idx; i < 64 * 64; i += stride) {
    int d = i / 64, j = i % 64;
    w[OFF_WQT + j * 64 + d] = Wq[d * 64 + j];
  }
  for (size_t i = idx; i < 192 * 64; i += stride) {
    int o = i / 64, j = i % 64;
    w[OFF_WIH + j * 192 + o] = Wih[o * 64 + j];
    w[OFF_WHH + j * 192 + o] = Whh[o * 64 + j];
  }
  for (size_t i = idx; i < 128 * 64; i += stride) {
    int o = i / 64, j = i % 64;
    w[OFF_F1T + j * 128 + o] = f1[o * 64 + j];
  }
  for (size_t i = idx; i < 64 * 128; i += stride) {
    int d = i / 128, j = i % 128;
    w[OFF_F2T + j * 64 + d] = f2[d * 128 + j];
  }
}

__launch_bounds__(1024, 4)
__global__ void slot_attn_kernel(
    const float* __restrict__ inputs, const float* __restrict__ sinit,
    const float* __restrict__ smu, const float* __restrict__ slsig,
    const float* __restrict__ Wk, const float* __restrict__ Wv,
    const float* __restrict__ gbih, const float* __restrict__ gbhh,
    const float* __restrict__ fc1b, const float* __restrict__ fc2b,
    const float* __restrict__ lin_g, const float* __restrict__ lin_b,
    const float* __restrict__ lsl_g, const float* __restrict__ lsl_b,
    const float* __restrict__ lff_g, const float* __restrict__ lff_b,
    const float* __restrict__ wi_W, const float* __restrict__ wi_b,
    const float* __restrict__ wsW, const float* __restrict__ wsB,
    float* __restrict__ out, float* __restrict__ w) {
  __shared__ float s_slots[448];
  __shared__ float s_snl[448];
  __shared__ float s_q[448];
  __shared__ float s_scr1[1344];
  __shared__ float s_scr2[1344];
  __shared__ float s_updl[448];
  __shared__ float s_T[8192];       // [1024][8]
  __shared__ float s_pupd[7168];    // [16][7][64]
  __shared__ float s_z[48];         // z_i = exp(v_i), i=0..5, stride 8
  __shared__ float s_eb[8];         // exp(log_b)
  __shared__ float s_rb[8];         // exp(-log_b)
  __shared__ float s_gvl[8];
  __shared__ float s_q2[8];
  __shared__ float s_wl[8];
  __shared__ float s_redw[128];     // [16][8] wave partials
  __shared__ float s_gath[128];     // [16][8] gathered block partials
  __shared__ float s_misc[4];

  const int tid = threadIdx.x;
  const int lane = tid & 63, wid = tid >> 6;
  const int bb = blockIdx.x & 15;   // batch
  const int ib16 = blockIdx.x >> 4; // 0..15 within batch group
  const size_t grow = (size_t)bb * CN + ib16 * 1024 + tid;
  u64x* st = reinterpret_cast<u64x*>(w);
  float lg;

  // ================= phase 0: LN + k/v/logit projections (block-local rows) ==
  {
    const float* xin = inputs + grow * 64;
    float4 xa[16];
#pragma unroll
    for (int c = 0; c < 16; ++c) xa[c] = reinterpret_cast<const float4*>(xin)[c];
    float s1 = 0;
#pragma unroll
    for (int c = 0; c < 16; ++c) s1 += xa[c].x + xa[c].y + xa[c].z + xa[c].w;
    float mn = s1 * (1.f / 64.f);
    float s2 = 0;
#pragma unroll
    for (int c = 0; c < 16; ++c) {
      float dx = xa[c].x - mn, dy = xa[c].y - mn, dz = xa[c].z - mn, dw = xa[c].w - mn;
      s2 += dx * dx + dy * dy + dz * dz + dw * dw;
    }
    float rs = rsqrtf(s2 * (1.f / 64.f) + 1e-5f);
#pragma unroll
    for (int c = 0; c < 16; ++c) {
      float4 g4 = reinterpret_cast<const float4*>(lin_g)[c];
      float4 b4 = reinterpret_cast<const float4*>(lin_b)[c];
      xa[c].x = (xa[c].x - mn) * rs * g4.x + b4.x;
      xa[c].y = (xa[c].y - mn) * rs * g4.y + b4.y;
      xa[c].z = (xa[c].z - mn) * rs * g4.z + b4.z;
      xa[c].w = (xa[c].w - mn) * rs * g4.w + b4.w;
    }
    lg = wi_b[0];
#pragma unroll
    for (int c = 0; c < 16; ++c) lg += dot4(xa[c], reinterpret_cast<const float4*>(wi_W)[c]);
#pragma unroll 1
    for (int half = 0; half < 2; ++half) {
      const float* W = half ? Wv : Wk;
      float* ob = w + (half ? OFF_V : OFF_K) + grow * 64;
#pragma unroll 1
      for (int oc = 0; oc < 8; ++oc) {
        float acc[8] = {0, 0, 0, 0, 0, 0, 0, 0};
#pragma unroll
        for (int c = 0; c < 16; ++c) {
          float4 xv = xa[c];
#pragma unroll
          for (int o8 = 0; o8 < 8; ++o8) {
            float4 w4 = reinterpret_cast<const float4*>(W + (size_t)(oc * 8 + o8) * 64)[c];
            acc[o8] += dot4(xv, w4);
          }
        }
        reinterpret_cast<float4*>(ob + oc * 8)[0] = make_float4(acc[0], acc[1], acc[2], acc[3]);
        reinterpret_cast<float4*>(ob + oc * 8)[1] = make_float4(acc[4], acc[5], acc[6], acc[7]);
      }
    }
    // block-local softmax stats for 'a'
    float mx = lg;
#pragma unroll
    for (int m = 1; m < 64; m <<= 1) mx = fmaxf(mx, __shfl_xor(mx, m, 64));
    float se = wsum64(__expf(lg - mx));
    if (lane == 0) { s_redw[wid * 8 + 0] = mx; s_redw[wid * 8 + 1] = se; }
    __syncthreads();
    if (wid == 0) {
      float m0 = (lane < 16) ? s_redw[lane * 8 + 0] : -1e30f;
      float e0 = (lane < 16) ? s_redw[lane * 8 + 1] : 0.f;
#pragma unroll
      for (int mm = 1; mm < 16; mm <<= 1) {
        float m1 = __shfl_xor(m0, mm, 64), e1 = __shfl_xor(e0, mm, 64);
        float nm = fmaxf(m0, m1);
        e0 = e0 * __expf(m0 - nm) + e1 * __expf(m1 - nm);
        m0 = nm;
      }
      if (lane == 0) {
        u64x* sp = st + ST1 + (size_t)(bb * 16 + ib16) * 4;
        st_rlx(sp + 0, pkf(m0, 1u));
        st_rlx(sp + 1, pkf(e0, 1u));
      }
    }
  }

  // ---- gather stats (16 blocks), compute global lse ----
  if (wid == 0) {
    int j = lane >> 2, f = lane & 3;
    if (f < 2) {
      s_gath[j * 4 + f] = poll_f(st + ST1 + (size_t)(bb * 16 + j) * 4 + f, 1u);
    }
  }
  __syncthreads();
  if (tid == 0) {
    float m = s_gath[0], se = s_gath[1];
#pragma unroll 1
    for (int j = 1; j < 16; ++j) {
      float mj = s_gath[j * 4], ej = s_gath[j * 4 + 1];
      float nm = fmaxf(m, mj);
      se = se * __expf(m - nm) + ej * __expf(mj - nm);
      m = nm;
    }
    s_misc[0] = m + __logf(se);
  }
  __syncthreads();
  const float aval = 7.f * __expf(lg - s_misc[0]);   // a[n] = 7*softmax(lg)

  unsigned e = 2;                    // epoch (phase-0 stats used 1)
  float p[7], E[7], eu = 0.f;

  // ---- stamped 16-block all-reduce of 7 per-thread values ----
  // dst semantics: div_eb ? dst[s] = eb[s]/tot[s]  (i.e. z = exp(logb - log R))
  //                       : dst[s] = tot[s]
  auto exchange = [&](float (&es)[7], float* dst, bool div_eb) {
#pragma unroll
    for (int m = 1; m < 64; m <<= 1) {
#pragma unroll
      for (int s = 0; s < 7; ++s) es[s] += __shfl_xor(es[s], m, 64);
    }
    if (lane == 0) {
#pragma unroll
      for (int s = 0; s < 7; ++s) s_redw[wid * 8 + s] = es[s];
    }
    __syncthreads();
    const unsigned par = e & 1;
    u64x* base = st + ST2 + ((size_t)(bb * 2 + par) * 16) * 8;
    if (wid == 0 && lane < 7) {
      float bp = 0.f;
#pragma unroll
      for (int j = 0; j < 16; ++j) bp += s_redw[j * 8 + lane];
      st_rlx(base + (size_t)ib16 * 8 + lane, pkf(bp, e));
    }
    if (wid < 2) {
      int g = wid * 64 + lane;
      int j = g >> 3, s2 = g & 7;
      if (s2 < 7) s_gath[j * 8 + s2] = poll_f(base + (size_t)j * 8 + s2, e);
    }
    __syncthreads();
    if (tid < 7) {
      float tot = 0.f;
#pragma unroll
      for (int j = 0; j < 16; ++j) tot += s_gath[j * 8 + tid];
      dst[tid] = div_eb ? (s_eb[tid] / tot) : tot;
    }
    __syncthreads();
    ++e;
  };

  // factored sinkhorn forward: 5 iterations; leaves eu = a/t5
  auto fwd5 = [&]() {
#pragma unroll 1
    for (int i = 1; i <= 5; ++i) {
      float t = 0.f;
#pragma unroll
      for (int s = 0; s < 7; ++s) t += E[s] * s_z[(i - 1) * 8 + s];
      eu = aval / t;
      float es[7];
#pragma unroll
      for (int s = 0; s < 7; ++s) es[s] = E[s] * eu;
      exchange(es, &s_z[i * 8], true);
    }
  };

  // slot phase common: LN(slots)->snl, q into LDS, eb/rb from log_b
  auto slot_common = [&]() {
    if (wid < 7) {
      float h = s_slots[wid * 64 + lane];
      float m = wsum64(h) * (1.f / 64.f);
      float d0 = h - m;
      float va = wsum64(d0 * d0) * (1.f / 64.f);
      float sn = d0 * rsqrtf(va + 1e-5f) * lsl_g[lane] + lsl_b[lane];
      s_snl[wid * 64 + lane] = sn;
      float pw = wsum64(sn * wsW[lane]);
      if (lane == 0) s_wl[wid] = pw + wsB[0];
    }
    __syncthreads();
    if (tid < 448) {
      int s = tid >> 6, dd = tid & 63;
      float acc = 0;
#pragma unroll 4
      for (int j = 0; j < 64; ++j) acc += s_snl[s * 64 + j] * w[OFF_WQT + j * 64 + dd];
      s_q[s * 64 + dd] = acc;
    }
    __syncthreads();
    if (wid < 7) {
      float qv = s_q[wid * 64 + lane];
      float q2 = wsum64(qv * qv);
      if (lane == 0) s_q2[wid] = q2;
    }
    if (tid == 0) {
      float mx = -1e30f;
#pragma unroll
      for (int s = 0; s < 7; ++s) mx = fmaxf(mx, s_wl[s]);
      float se = 0;
#pragma unroll
      for (int s = 0; s < 7; ++s) se += __expf(s_wl[s] - mx);
      float lse = mx + __logf(se);
#pragma unroll
      for (int s = 0; s < 7; ++s) {
        float ebv = __expf(s_wl[s] - lse + LOG7);   // exp(log_b)
        s_eb[s] = ebv;
        s_rb[s] = 1.f / ebv;
      }
    }
    __syncthreads();
  };

  // init slots
  if (tid < 448) {
    int dd = tid & 63;
    s_slots[tid] = smu[dd] + __expf(slsig[dd]) * sinit[(size_t)bb * 448 + tid];
  }
  __syncthreads();
  slot_common();

#pragma unroll 1
  for (int it = 0; it < 3; ++it) {
    // ---- C = -cdist(k, q); E = exp(p) ----
    {
      const float* kb = w + OFF_K + grow * 64;
      float4 ka[16];
#pragma unroll
      for (int c = 0; c < 16; ++c) ka[c] = reinterpret_cast<const float4*>(kb)[c];
      float k2 = 0;
#pragma unroll
      for (int c = 0; c < 16; ++c) k2 += dot4(ka[c], ka[c]);
#pragma unroll
      for (int s = 0; s < 7; ++s) {
        float kq = 0;
#pragma unroll
        for (int c = 0; c < 16; ++c)
          kq += dot4(ka[c], *reinterpret_cast<const float4*>(&s_q[s * 64 + c * 4]));
        float sq = k2 + s_q2[s] - 2.f * kq;
        p[s] = -sqrtf(fmaxf(sq, 0.f) + 1e-12f);
        E[s] = __expf(p[s]);
      }
    }
    if (tid < 8) s_z[tid] = 1.f;     // v_0 = 0
    __syncthreads();

    // ---- MESH: 4 iterations of entropy-gradient descent on C ----
#pragma unroll 1
    for (int ms = 0; ms < 4; ++ms) {
      fwd5();
      float gp[7], guT = 0.f;
      {
        float es[7];
#pragma unroll
        for (int s = 0; s < 7; ++s) {
          float T = E[s] * eu * s_z[40 + s];
          float gT = -(__logf(T + EPST) + T / (T + EPST));
          float g = gT * T;
          gp[s] = g; guT += g; es[s] = g;
        }
        exchange(es, s_gvl, false);   // gv_5
      }
#pragma unroll 1
      for (int i = 5; i >= 1; --i) {
        float t = 0.f;
#pragma unroll
        for (int s = 0; s < 7; ++s) t += E[s] * s_z[(i - 1) * 8 + s];
        float rt = 1.f / t;
        float eui = aval * rt;
        float gu = (i == 5) ? guT : 0.f;
#pragma unroll
        for (int s = 0; s < 7; ++s) {
          float sn = E[s] * eui * s_z[i * 8 + s] * s_rb[s];
          float gz = -s_gvl[s] * sn;
          gp[s] += gz; gu += gz;
        }
        float gw[7];
#pragma unroll
        for (int s = 0; s < 7; ++s) {
          float sg = E[s] * s_z[(i - 1) * 8 + s] * rt;
          gw[s] = -gu * sg;
          gp[s] += gw[s];
        }
        if (i > 1) exchange(gw, s_gvl, false);  // gv_{i-1}
      }
#pragma unroll
      for (int s = 0; s < 7; ++s) {
        p[s] -= 5.0f * gp[s];
        E[s] = __expf(p[s]);
      }
      if (tid < 8) s_z[tid] = s_z[40 + tid];    // warm-start v
      __syncthreads();
    }

    // ---- final sinkhorn (warm-started) -> attn row ----
    fwd5();
    float T7[7];
#pragma unroll
    for (int s = 0; s < 7; ++s) T7[s] = E[s] * eu * s_z[40 + s];
    if (it == 2) {
      size_t ab = 7168 + (size_t)(bb * 7) * CN + ib16 * 1024 + tid;
#pragma unroll
      for (int s = 0; s < 7; ++s) out[ab + (size_t)s * CN] = T7[s];
    }
#pragma unroll
    for (int s = 0; s < 7; ++s) s_T[tid * 8 + s] = T7[s];
    __syncthreads();

    // ---- updates = attn @ v (per-wave column reduce, then group combine) ----
    {
      const float* vb = w + OFF_V + (grow - tid + wid * 64) * 64 + lane;
      float acc[7] = {0, 0, 0, 0, 0, 0, 0};
#pragma unroll 4
      for (int n = 0; n < 64; ++n) {
        float vv = vb[(size_t)n * 64];
        const float* tr = &s_T[(wid * 64 + n) * 8];
        acc[0] += tr[0] * vv; acc[1] += tr[1] * vv; acc[2] += tr[2] * vv;
        acc[3] += tr[3] * vv; acc[4] += tr[4] * vv; acc[5] += tr[5] * vv;
        acc[6] += tr[6] * vv;
      }
#pragma unroll
      for (int s = 0; s < 7; ++s) s_pupd[(wid * 7 + s) * 64 + lane] = acc[s];
    }
    __syncthreads();
    {
      const unsigned par = e & 1;
      u64x* b3 = st + ST3 + ((size_t)(bb * 2 + par) * 16) * 448;
      if (tid < 448) {
        float t = 0;
#pragma unroll
        for (int w16 = 0; w16 < 16; ++w16) t += s_pupd[w16 * 448 + tid];
        st_rlx(b3 + (size_t)ib16 * 448 + tid, pkf(t, e));
        // parallel-retry poll: 16 independent loads per round
        float tot; bool ok;
        do {
          tot = 0.f; ok = true;
#pragma unroll
          for (int j = 0; j < 16; ++j) {
            u64x q = ld_rlx(b3 + (size_t)j * 448 + tid);
            ok = ok && ((unsigned)(q >> 32) == e);
            tot += __uint_as_float((unsigned)q);
          }
        } while (!ok);
        s_updl[tid] = tot;
      }
      __syncthreads();
      ++e;
    }

    // ---- GRU cell + FF (redundant per block) ----
    {
#pragma unroll 1
      for (int idx = tid; idx < 1344; idx += 1024) {
        int s = idx / 192, o = idx - s * 192;
        float g1 = gbih[o], g2 = gbhh[o];
#pragma unroll 4
        for (int j = 0; j < 64; ++j) {
          g1 += s_updl[s * 64 + j] * w[OFF_WIH + j * 192 + o];
          g2 += s_slots[s * 64 + j] * w[OFF_WHH + j * 192 + o];
        }
        s_scr1[s * 192 + o] = g1;
        s_scr2[s * 192 + o] = g2;
      }
      __syncthreads();
      if (tid < 448) {
        int s = tid >> 6, dd = tid & 63;
        float ir = s_scr1[s * 192 + dd],        hr = s_scr2[s * 192 + dd];
        float iz = s_scr1[s * 192 + 64 + dd],   hz = s_scr2[s * 192 + 64 + dd];
        float in_ = s_scr1[s * 192 + 128 + dd], hn = s_scr2[s * 192 + 128 + dd];
        float r = 1.f / (1.f + __expf(-(ir + hr)));
        float z = 1.f / (1.f + __expf(-(iz + hz)));
        float nn = tanhf(in_ + r * hn);
        s_updl[s * 64 + dd] = (1.f - z) * nn + z * s_slots[s * 64 + dd];
      }
      __syncthreads();
      if (wid < 7) {
        float h = s_updl[wid * 64 + lane];
        float m = wsum64(h) * (1.f / 64.f);
        float d0 = h - m;
        float va = wsum64(d0 * d0) * (1.f / 64.f);
        s_snl[wid * 64 + lane] = d0 * rsqrtf(va + 1e-5f) * lff_g[lane] + lff_b[lane];
      }
      __syncthreads();
      if (tid < 896) {
        int s = tid >> 7, i2 = tid & 127;
        float a1 = fc1b[i2];
#pragma unroll 4
        for (int j = 0; j < 64; ++j) a1 += s_snl[s * 64 + j] * w[OFF_F1T + j * 128 + i2];
        s_scr1[s * 128 + i2] = fmaxf(a1, 0.f);
      }
      __syncthreads();
      if (tid < 448) {
        int s = tid >> 6, dd = tid & 63;
        float a2 = fc2b[dd];
#pragma unroll 4
        for (int i2 = 0; i2 < 128; ++i2) a2 += s_scr1[s * 128 + i2] * w[OFF_F2T + i2 * 64 + dd];
        s_slots[s * 64 + dd] = s_updl[s * 64 + dd] + a2;
      }
      __syncthreads();
    }
    if (it < 2) slot_common();
  }

  if (ib16 == 0 && tid < 448) out[(size_t)bb * 448 + tid] = s_slots[tid];
}

extern "C" void kernel_launch(void* const* d_in, const int* in_sizes, int n_in,
                              void* d_out, int out_size, void* d_ws, size_t ws_size,
                              hipStream_t stream) {
  (void)in_sizes; (void)n_in; (void)out_size; (void)ws_size;
  const float* inputs = (const float*)d_in[0];
  const float* sinit  = (const float*)d_in[1];
  const float* smu    = (const float*)d_in[2];
  const float* slsig  = (const float*)d_in[3];
  const float* Wq     = (const float*)d_in[4];
  const float* Wk     = (const float*)d_in[5];
  const float* Wv     = (const float*)d_in[6];
  const float* gWih   = (const float*)d_in[7];
  const float* gWhh   = (const float*)d_in[8];
  const float* gbih   = (const float*)d_in[9];
  const float* gbhh   = (const float*)d_in[10];
  const float* fc1W   = (const float*)d_in[11];
  const float* fc1b   = (const float*)d_in[12];
  const float* fc2W   = (const float*)d_in[13];
  const float* fc2b   = (const float*)d_in[14];
  const float* ling   = (const float*)d_in[15];
  const float* linb   = (const float*)d_in[16];
  const float* lslg   = (const float*)d_in[17];
  const float* lslb   = (const float*)d_in[18];
  const float* lffg   = (const float*)d_in[19];
  const float* lffb   = (const float*)d_in[20];
  const float* wiW    = (const float*)d_in[21];
  const float* wib    = (const float*)d_in[22];
  const float* wsW    = (const float*)d_in[23];
  const float* wsb    = (const float*)d_in[24];
  float* out = (float*)d_out;
  float* w   = (float*)d_ws;

  prep_kernel<<<dim3(64), dim3(256), 0, stream>>>(Wq, gWih, gWhh, fc1W, fc2W, w);
  slot_attn_kernel<<<dim3(256), dim3(1024), 0, stream>>>(
      inputs, sinit, smu, slsig, Wk, Wv, gbih, gbhh, fc1b, fc2b,
      ling, linb, lslg, lslb, lffg, lffb, wiW, wib, wsW, wsb, out, w);
}